// Round 10
// baseline (137.291 us; speedup 1.0000x reference)
//
#include <hip/hip_runtime.h>
#include <hip/hip_fp16.h>
#include <math.h>

#define KSIZE 31
#define HRAD 15
#define NBINS 33   // blend maps at m = 2 + k/32, k = 0..32

union H4U { float2 f2; __half h[4]; };
union H8U { float4 f4; __half h[8]; };

// ---------------------------------------------------------------------------
// Cube-map coordinate math (mirrors reference cube_sample exactly, f32)
// ---------------------------------------------------------------------------
__device__ inline void cube_coords(float x, float y, float z,
                                   int& face, float& u, float& v) {
    float ax = fabsf(x), ay = fabsf(y), az = fabsf(z);
    bool is_x = (ax >= ay) && (ax >= az);
    bool is_y = (!is_x) && (ay >= az);
    float ma, sc, tc;
    if (is_x) {
        if (x >= 0.0f) { face = 0; sc = -z; } else { face = 1; sc = z; }
        ma = ax; tc = -y;
    } else if (is_y) {
        if (y >= 0.0f) { face = 2; tc = z; } else { face = 3; tc = -z; }
        ma = ay; sc = x;
    } else {
        if (z >= 0.0f) { face = 4; sc = x; } else { face = 5; sc = -x; }
        ma = az; tc = -y;
    }
    float inv = 1.0f / fmaxf(ma, 1e-12f);
    u = 0.5f * (sc * inv + 1.0f);
    v = 0.5f * (tc * inv + 1.0f);
}

// ---------------------------------------------------------------------------
// bg0 neighborhood records: per texel (x,y), 32B = 4 half4 corners.
// rec = (face*HW + y)*HW + x ; corners clamped at build; left/top edge
// handled by forcing wx/wy = 0 (exact).
// ---------------------------------------------------------------------------
__device__ inline void nb_setup(float u, float v, int HW, int face,
                                int& rec, float& wx, float& wy) {
    float fx = u * (float)HW - 0.5f;
    float fy = v * (float)HW - 0.5f;
    float x0 = floorf(fx), y0 = floorf(fy);
    wx = fx - x0;
    wy = fy - y0;
    int xi = (int)x0, yi = (int)y0;
    if (xi < 0) { xi = 0; wx = 0.0f; }
    if (yi < 0) { yi = 0; wy = 0.0f; }
    rec = (face * HW + yi) * HW + xi;
}

__device__ inline void nb_fetch(const float4* __restrict__ nb, int rec,
                                float wx, float wy, float c[3]) {
    H8U qa, qb;
    qa.f4 = nb[(size_t)rec * 2 + 0];
    qb.f4 = nb[(size_t)rec * 2 + 1];
#pragma unroll
    for (int k = 0; k < 3; ++k) {
        float top = __half2float(qa.h[k]) * (1.0f - wx) + __half2float(qa.h[4 + k]) * wx;
        float bot = __half2float(qb.h[k]) * (1.0f - wx) + __half2float(qb.h[4 + k]) * wx;
        c[k] = top * (1.0f - wy) + bot * wy;
    }
}

// ---------------------------------------------------------------------------
// Inline f32 Gaussian weights (tid 0..127 -> lvl=tid/32, tap=tid%32)
// ---------------------------------------------------------------------------
__device__ inline void weights_inline(int tid, float wS[4][32]) {
    const float ss[4] = {8.f, 4.f, 2.f, 1.f};
    int lvl = (tid >> 5) & 3;
    int tap = tid & 31;
    float d = (float)tap - 15.0f;
    float q = d / ss[lvl];
    float g = (tap < KSIZE) ? expf(-0.5f * q * q) : 0.0f;
    float s = g;
#pragma unroll
    for (int k = 16; k; k >>= 1) s += __shfl_xor(s, k, 32);
    if (tid < 128) wS[lvl][tap] = g / s;
}

// ---------------------------------------------------------------------------
// FUSED prep kernel:
//   blocks [0, 6144)    : bg1 row-pair pack (16B rec = [t(x,y), t(x+1|,y)])
//   blocks [6144, 6528) : horizontal 4-level blur (2 rows/block) + bg0n emit
// tmpH: per 128-texel 32B = {lvl0 rgb, lvl1 rgb | lvl2 rgb, lvl3 rgb} halves
// ---------------------------------------------------------------------------
__global__ __launch_bounds__(256)
void prep1(const float* __restrict__ bg0, const float* __restrict__ bg1,
           float4* __restrict__ tmpH, float4* __restrict__ bg0n,
           float4* __restrict__ bg1rp) {
    __shared__ float sm[1664];
    int b = blockIdx.x;
    int tid = threadIdx.x;

    if (b < 6144) {
        // ---- bg1 row-pair pack: one 256-texel row segment per block ----
        int half = b & 1;
        int y    = (b >> 1) & 511;
        int f    = b >> 10;
        int x0   = half * 256;
        const float* rowp = bg1 + (size_t)(f * 512 + y) * 512 * 3;
        // stage 257 texels (771 floats), clamped at row end
        for (int k = tid; k < 771; k += 256) {
            int gx = min(x0 + k / 3, 511);
            sm[k] = rowp[gx * 3 + (k - (k / 3) * 3)];
        }
        __syncthreads();
        int t0 = tid * 3;
        H8U r;
#pragma unroll
        for (int k = 0; k < 3; ++k) {
            r.h[k]     = __float2half(sm[t0 + k]);
            r.h[4 + k] = __float2half(sm[t0 + 3 + k]);
        }
        r.h[3] = __float2half(0.0f); r.h[7] = __float2half(0.0f);
        bg1rp[(size_t)(f * 512 + y) * 512 + x0 + tid] = r.f4;
        return;
    }

    // ---- horizontal blur branch: 2 rows per block ----
    float (*rows)[2][384] = (float (*)[2][384])sm;
    float (*wS)[32] = (float (*)[32])(sm + 1536);

    int bid  = b - 6144;               // 0..383
    int unit = tid >> 7;               // 0 or 1
    int lane = tid & 127;
    int face = bid / 64;
    int yrow = (bid % 64) * 2 + unit;

    weights_inline(tid, wS);

    int ynext = min(yrow + 1, 127);
    const float* srcA = bg0 + (size_t)(face * 128 + yrow) * 384;
    const float* srcB = bg0 + (size_t)(face * 128 + ynext) * 384;
    for (int k = lane; k < 384; k += 128) {
        rows[unit][0][k] = srcA[k];
        rows[unit][1][k] = srcB[k];
    }
    __syncthreads();

    int x = lane;
    float a[4][3] = {};
    for (int t = 0; t < KSIZE; ++t) {
        int xx = x + t - HRAD;
        if (xx >= 0 && xx < 128) {
            float r0 = rows[unit][0][xx * 3 + 0];
            float r1 = rows[unit][0][xx * 3 + 1];
            float r2 = rows[unit][0][xx * 3 + 2];
#pragma unroll
            for (int l = 0; l < 4; ++l) {
                float w = wS[l][t];
                a[l][0] += w * r0; a[l][1] += w * r1; a[l][2] += w * r2;
            }
        }
    }
    size_t idx = (size_t)(face * 128 + yrow) * 128 + x;
    H8U ta, tb;
#pragma unroll
    for (int l = 0; l < 2; ++l) {
        ta.h[l * 4 + 0] = __float2half(a[l][0]);
        ta.h[l * 4 + 1] = __float2half(a[l][1]);
        ta.h[l * 4 + 2] = __float2half(a[l][2]);
        ta.h[l * 4 + 3] = __float2half(0.0f);
        tb.h[l * 4 + 0] = __float2half(a[2 + l][0]);
        tb.h[l * 4 + 1] = __float2half(a[2 + l][1]);
        tb.h[l * 4 + 2] = __float2half(a[2 + l][2]);
        tb.h[l * 4 + 3] = __float2half(0.0f);
    }
    tmpH[idx * 2 + 0] = ta.f4;
    tmpH[idx * 2 + 1] = tb.f4;

    // bg0 neighborhood record for (x, yrow)
    int x1 = min(x + 1, 127);
    H8U qa, qb;
#pragma unroll
    for (int k = 0; k < 3; ++k) {
        qa.h[k]     = __float2half(rows[unit][0][x * 3 + k]);
        qa.h[4 + k] = __float2half(rows[unit][0][x1 * 3 + k]);
        qb.h[k]     = __float2half(rows[unit][1][x * 3 + k]);
        qb.h[4 + k] = __float2half(rows[unit][1][x1 * 3 + k]);
    }
    qa.h[3] = __float2half(0.0f); qa.h[7] = __float2half(0.0f);
    qb.h[3] = __float2half(0.0f); qb.h[7] = __float2half(0.0f);
    bg0n[idx * 2 + 0] = qa.f4;
    bg0n[idx * 2 + 1] = qb.f4;
}

// ---------------------------------------------------------------------------
// Vertical blur + bin emit: one output row per block. Computes the 4 level
// values, then writes 33 pre-normalized blend maps (weights compile-time-ish).
// bins[k][(face*128+y)*128+x] : half4 (float2), k = 0..32 <-> m = 2 + k/32.
// ---------------------------------------------------------------------------
__global__ __launch_bounds__(128)
void blur_v4bins(const float4* __restrict__ tmpH, float2* __restrict__ bins) {
    __shared__ float wS[4][32];
    int bid  = blockIdx.x;
    int yrow = bid & 127;
    int face = bid >> 7;
    int tid  = threadIdx.x;

    weights_inline(tid, wS);
    __syncthreads();

    int x = tid;
    float acc[12] = {};
    int ylo = max(yrow - HRAD, 0);
    int yhi = min(yrow + HRAD, 127);
    for (int yy = ylo; yy <= yhi; ++yy) {
        int t = yy - yrow + HRAD;
        size_t idx = (size_t)(face * 128 + yy) * 128 + x;
        H8U qa, qb;
        qa.f4 = tmpH[idx * 2 + 0];
        qb.f4 = tmpH[idx * 2 + 1];
        float w0 = wS[0][t], w1 = wS[1][t], w2 = wS[2][t], w3 = wS[3][t];
        acc[0]  += w0 * __half2float(qa.h[0]);
        acc[1]  += w0 * __half2float(qa.h[1]);
        acc[2]  += w0 * __half2float(qa.h[2]);
        acc[3]  += w1 * __half2float(qa.h[4]);
        acc[4]  += w1 * __half2float(qa.h[5]);
        acc[5]  += w1 * __half2float(qa.h[6]);
        acc[6]  += w2 * __half2float(qb.h[0]);
        acc[7]  += w2 * __half2float(qb.h[1]);
        acc[8]  += w2 * __half2float(qb.h[2]);
        acc[9]  += w3 * __half2float(qb.h[4]);
        acc[10] += w3 * __half2float(qb.h[5]);
        acc[11] += w3 * __half2float(qb.h[6]);
    }

    int rec = (face * 128 + yrow) * 128 + x;
    for (int k = 0; k < NBINS; ++k) {
        float mc = 2.0f + (float)k * 0.03125f;
        float w0 = 1.0f - fminf(fabsf(3.0f - mc), 1.0f);
        float w1 = 1.0f - fminf(fabsf(2.5f - mc), 1.0f);
        float w2 = 1.0f - fminf(fabsf(2.0f - mc), 1.0f);
        float w3 = 1.0f - fminf(fabsf(1.5f - mc), 1.0f);
        float inv = 1.0f / fmaxf(w0 + w1 + w2 + w3, 1e-8f);
        H4U o;
        o.h[0] = __float2half((w0 * acc[0] + w1 * acc[3] + w2 * acc[6] + w3 * acc[9])  * inv);
        o.h[1] = __float2half((w0 * acc[1] + w1 * acc[4] + w2 * acc[7] + w3 * acc[10]) * inv);
        o.h[2] = __float2half((w0 * acc[2] + w1 * acc[5] + w2 * acc[8] + w3 * acc[11]) * inv);
        o.h[3] = __float2half(0.0f);
        bins[(size_t)k * 98304 + rec] = o.f2;
    }
}

// ---------------------------------------------------------------------------
// Per-ray shading
// ---------------------------------------------------------------------------
__device__ inline void shade_ray(float x, float y, float z, float sa,
                                 const float4* __restrict__ bg0n,
                                 const float4* __restrict__ bg1rp,
                                 const float2* __restrict__ bins,
                                 float* __restrict__ R) {
    int face; float u, v;
    cube_coords(x, y, z, face, u, v);

    const float saTexel = (float)(4.0 * M_PI / (6.0 * 512.0 * 512.0));
    float m = logf(sa / saTexel);
    m = m / 1.3862943611198906f;   // f32(log(4))
    m = m * 0.5f;
    m = fminf(fmaxf(m, 0.0f), 3.0f);

    if (m >= 2.0f) {
        // nearest blend map (exact at m=2.0 and m=3.0), plain bilinear: 4 loads
        int k = (int)((m - 2.0f) * 32.0f + 0.5f);
        const float2* bm = bins + (size_t)k * 98304;
        float fx = u * 128.0f - 0.5f;
        float fy = v * 128.0f - 0.5f;
        float xf = floorf(fx), yf = floorf(fy);
        float wx = fx - xf, wy = fy - yf;
        int x0i = min(max((int)xf, 0), 127);
        int x1i = min(max((int)xf + 1, 0), 127);
        int y0i = min(max((int)yf, 0), 127);
        int y1i = min(max((int)yf + 1, 0), 127);
        int base = face << 14;
        H4U t00, t10, t01, t11;
        t00.f2 = bm[base + y0i * 128 + x0i];
        t10.f2 = bm[base + y0i * 128 + x1i];
        t01.f2 = bm[base + y1i * 128 + x0i];
        t11.f2 = bm[base + y1i * 128 + x1i];
#pragma unroll
        for (int c = 0; c < 3; ++c) {
            float top = __half2float(t00.h[c]) * (1.0f - wx) + __half2float(t10.h[c]) * wx;
            float bot = __half2float(t01.h[c]) * (1.0f - wx) + __half2float(t11.h[c]) * wx;
            R[c] = top * (1.0f - wy) + bot * wy;
        }
    } else {
        // bg0 nbhd record: 2 loads
        int r0i; float wx0, wy0;
        nb_setup(u, v, 128, face, r0i, wx0, wy0);
        float c0[3];
        nb_fetch(bg0n, r0i, wx0, wy0, c0);

        // bg1 row-pair records: 2 loads
        float fx = u * 512.0f - 0.5f;
        float fy = v * 512.0f - 0.5f;
        float xf = floorf(fx), yf = floorf(fy);
        float wx = fx - xf, wy = fy - yf;
        int xi = (int)xf, yi = (int)yf;
        if (xi < 0) { xi = 0; wx = 0.0f; }
        if (yi < 0) { yi = 0; wy = 0.0f; }
        int y1i = min(yi + 1, 511);
        H8U ra, rb;
        ra.f4 = bg1rp[(size_t)(face * 512 + yi)  * 512 + xi];
        rb.f4 = bg1rp[(size_t)(face * 512 + y1i) * 512 + xi];
#pragma unroll
        for (int c = 0; c < 3; ++c) {
            float top = __half2float(ra.h[c]) * (1.0f - wx) + __half2float(ra.h[4 + c]) * wx;
            float bot = __half2float(rb.h[c]) * (1.0f - wx) + __half2float(rb.h[4 + c]) * wx;
            float c1 = top * (1.0f - wy) + bot * wy;
            R[c] = c0[c] + 0.5f * c1;
        }
    }
}

// ---------------------------------------------------------------------------
// Shade: 4 rays per thread, vectorized stream I/O.
// ---------------------------------------------------------------------------
__global__ __launch_bounds__(256)
void shade4(const float4* __restrict__ vd4, const float4* __restrict__ sa4,
            const float4* __restrict__ bg0n, const float4* __restrict__ bg1rp,
            const float2* __restrict__ bins, float4* __restrict__ out4,
            int nquads) {
    int q = blockIdx.x * blockDim.x + threadIdx.x;
    if (q >= nquads) return;

    float4 a = vd4[3 * q + 0];
    float4 b = vd4[3 * q + 1];
    float4 c = vd4[3 * q + 2];
    float4 s = sa4[q];

    float X[4] = {a.x, a.w, b.z, c.y};
    float Y[4] = {a.y, b.x, b.w, c.z};
    float Z[4] = {a.z, b.y, c.x, c.w};
    float S[4] = {s.x, s.y, s.z, s.w};

    float R[12];
#pragma unroll
    for (int r = 0; r < 4; ++r) {
        shade_ray(X[r], Y[r], Z[r], S[r], bg0n, bg1rp, bins, &R[3 * r]);
    }

    out4[3 * q + 0] = make_float4(R[0], R[1], R[2],  R[3]);
    out4[3 * q + 1] = make_float4(R[4], R[5], R[6],  R[7]);
    out4[3 * q + 2] = make_float4(R[8], R[9], R[10], R[11]);
}

// ---------------------------------------------------------------------------
extern "C" void kernel_launch(void* const* d_in, const int* in_sizes, int n_in,
                              void* d_out, int out_size, void* d_ws, size_t ws_size,
                              hipStream_t stream) {
    const float* viewdirs = (const float*)d_in[0];   // (B,3)
    const float* saSample = (const float*)d_in[1];   // (B,1)
    const float* bg0      = (const float*)d_in[2];   // (6,128,128,3)
    const float* bg1      = (const float*)d_in[3];   // (6,512,512,3)
    float* out = (float*)d_out;

    int B = in_sizes[0] / 3;          // 2097152
    int nquads = B / 4;

    // ws layout (57.4 MB total; 59.77 MB proven available in r9):
    //   bins  : 33 * 98304 float2 = 3,244,032 f2 (26.0 MB)
    //   bg1rp : 1,572,864 float4            (25.2 MB)
    //   bg0n  : 196,608 float4              (3.0 MB)
    //   tmpH  : 196,608 float4              (3.0 MB)
    float2* bins  = (float2*)d_ws;
    float4* bg1rp = (float4*)(bins + (size_t)NBINS * 98304);
    float4* bg0n  = bg1rp + 1572864;
    float4* tmpH  = bg0n + 196608;

    prep1<<<6528, 256, 0, stream>>>(bg0, bg1, tmpH, bg0n, bg1rp);
    blur_v4bins<<<6 * 128, 128, 0, stream>>>(tmpH, bins);

    int blocks = (nquads + 255) / 256;
    shade4<<<blocks, 256, 0, stream>>>((const float4*)viewdirs,
                                       (const float4*)saSample,
                                       bg0n, bg1rp, bins,
                                       (float4*)out, nquads);
}

// Round 11
// 105.572 us; speedup vs baseline: 1.3005x; 1.3005x over previous
//
#include <hip/hip_runtime.h>
#include <hip/hip_fp16.h>
#include <math.h>

#define KSIZE 31
#define HRAD 15

union H4U { float2 f2; __half h[4]; };
union H8U { float4 f4; __half h[8]; };

// ---------------------------------------------------------------------------
// Cube-map coordinate math (mirrors reference cube_sample exactly, f32)
// ---------------------------------------------------------------------------
__device__ inline void cube_coords(float x, float y, float z,
                                   int& face, float& u, float& v) {
    float ax = fabsf(x), ay = fabsf(y), az = fabsf(z);
    bool is_x = (ax >= ay) && (ax >= az);
    bool is_y = (!is_x) && (ay >= az);
    float ma, sc, tc;
    if (is_x) {
        if (x >= 0.0f) { face = 0; sc = -z; } else { face = 1; sc = z; }
        ma = ax; tc = -y;
    } else if (is_y) {
        if (y >= 0.0f) { face = 2; tc = z; } else { face = 3; tc = -z; }
        ma = ay; sc = x;
    } else {
        if (z >= 0.0f) { face = 4; sc = x; } else { face = 5; sc = -x; }
        ma = az; tc = -y;
    }
    float inv = 1.0f / fmaxf(ma, 1e-12f);
    u = 0.5f * (sc * inv + 1.0f);
    v = 0.5f * (tc * inv + 1.0f);
}

// ---------------------------------------------------------------------------
// Neighborhood records: per texel (x,y), 32B = 4 half4 corners.
// rec = (face*HW + y)*HW + x ; corners clamped at build; left/top edge
// handled by forcing wx/wy = 0 (exact).
// ---------------------------------------------------------------------------
__device__ inline void nb_setup(float u, float v, int HW, int face,
                                int& rec, float& wx, float& wy) {
    float fx = u * (float)HW - 0.5f;
    float fy = v * (float)HW - 0.5f;
    float x0 = floorf(fx), y0 = floorf(fy);
    wx = fx - x0;
    wy = fy - y0;
    int xi = (int)x0, yi = (int)y0;
    if (xi < 0) { xi = 0; wx = 0.0f; }
    if (yi < 0) { yi = 0; wy = 0.0f; }
    rec = (face * HW + yi) * HW + xi;
}

__device__ inline void nb_fetch(const float4* __restrict__ nb, int rec,
                                float wx, float wy, float c[3]) {
    H8U qa, qb;
    qa.f4 = nb[(size_t)rec * 2 + 0];
    qb.f4 = nb[(size_t)rec * 2 + 1];
#pragma unroll
    for (int k = 0; k < 3; ++k) {
        float top = __half2float(qa.h[k]) * (1.0f - wx) + __half2float(qa.h[4 + k]) * wx;
        float bot = __half2float(qb.h[k]) * (1.0f - wx) + __half2float(qb.h[4 + k]) * wx;
        c[k] = top * (1.0f - wy) + bot * wy;
    }
}

// ---------------------------------------------------------------------------
// Interleaved blur records: per 128-map texel, 4 levels x half4 = 32B.
// rec = ((face*64 + y/2)*128 + x)*2 + (y&1)
// ---------------------------------------------------------------------------
struct BLR {
    int r00, r10, r01, r11;
    float wx, wy;
};

__device__ inline BLR bl_rec(float u, float v, int face) {
    float fx = u * 128.0f - 0.5f;
    float fy = v * 128.0f - 0.5f;
    float x0 = floorf(fx), y0 = floorf(fy);
    BLR b;
    b.wx = fx - x0;
    b.wy = fy - y0;
    int x0i = min(max((int)x0, 0), 127);
    int x1i = min(max((int)x0 + 1, 0), 127);
    int y0i = min(max((int)y0, 0), 127);
    int y1i = min(max((int)y0 + 1, 0), 127);
    int fb = face * 64;
    int r0 = (fb + (y0i >> 1)) * 128;
    int r1 = (fb + (y1i >> 1)) * 128;
    b.r00 = (r0 + x0i) * 2 + (y0i & 1);
    b.r10 = (r0 + x1i) * 2 + (y0i & 1);
    b.r01 = (r1 + x0i) * 2 + (y1i & 1);
    b.r11 = (r1 + x1i) * 2 + (y1i & 1);
    return b;
}

__device__ inline void accum_level(const H8U& q00, const H8U& q10,
                                   const H8U& q01, const H8U& q11,
                                   int off, float w, float wx, float wy,
                                   float& b0, float& b1, float& b2) {
    float c[3];
#pragma unroll
    for (int k = 0; k < 3; ++k) {
        float top = __half2float(q00.h[off + k]) * (1.0f - wx) + __half2float(q10.h[off + k]) * wx;
        float bot = __half2float(q01.h[off + k]) * (1.0f - wx) + __half2float(q11.h[off + k]) * wx;
        c[k] = top * (1.0f - wy) + bot * wy;
    }
    b0 += w * c[0];
    b1 += w * c[1];
    b2 += w * c[2];
}

// ---------------------------------------------------------------------------
// Inline f32 Gaussian weights (tid 0..127 -> lvl=tid/32, tap=tid%32)
// ---------------------------------------------------------------------------
__device__ inline void weights_inline(int tid, float wS[4][32]) {
    const float ss[4] = {8.f, 4.f, 2.f, 1.f};
    int lvl = (tid >> 5) & 3;
    int tap = tid & 31;
    float d = (float)tap - 15.0f;
    float q = d / ss[lvl];
    float g = (tap < KSIZE) ? expf(-0.5f * q * q) : 0.0f;
    float s = g;
#pragma unroll
    for (int k = 16; k; k >>= 1) s += __shfl_xor(s, k, 32);
    if (tid < 128) wS[lvl][tap] = g / s;
}

// ---------------------------------------------------------------------------
// FUSED prep kernel:
//   blocks [0, 6144)    : bg1 nbhd-record pack, ROW-RUN layout.
//       block = (face, y, half): stages rows y and y+1 (257 texels each,
//       clamped) contiguously in LDS, emits 256 consecutive 32B records ->
//       fully dense coalesced reads AND writes.
//   blocks [6144, 6528) : horizontal 4-level blur (2 rows/block) + bg0n emit
// tmpH: per 128-texel 32B = {lvl0 rgb, lvl1 rgb | lvl2 rgb, lvl3 rgb} halves
// ---------------------------------------------------------------------------
__global__ __launch_bounds__(256)
void prep1(const float* __restrict__ bg0, const float* __restrict__ bg1,
           float4* __restrict__ tmpH, float4* __restrict__ bg0n,
           float4* __restrict__ bg1n) {
    __shared__ float sm[1664];
    int b = blockIdx.x;
    int tid = threadIdx.x;

    if (b < 6144) {
        // ---- bg1 nbhd pack: one 256-texel row segment per block ----
        float* smA = sm;          // row y   : 771 floats
        float* smB = sm + 771;    // row y+1 : 771 floats
        int half = b & 1;
        int y    = (b >> 1) & 511;
        int f    = b >> 10;
        int x0   = half * 256;
        int yn   = min(y + 1, 511);
        const float* rowA = bg1 + (size_t)(f * 512 + y)  * 1536;
        const float* rowB = bg1 + (size_t)(f * 512 + yn) * 1536;
        for (int k = tid; k < 771; k += 256) {
            int t = k / 3;
            int c = k - t * 3;
            int gx = min(x0 + t, 511);
            smA[k] = rowA[gx * 3 + c];
            smB[k] = rowB[gx * 3 + c];
        }
        __syncthreads();
        int t0 = tid * 3;
        H8U qa, qb;
#pragma unroll
        for (int k = 0; k < 3; ++k) {
            qa.h[k]     = __float2half(smA[t0 + k]);
            qa.h[4 + k] = __float2half(smA[t0 + 3 + k]);
            qb.h[k]     = __float2half(smB[t0 + k]);
            qb.h[4 + k] = __float2half(smB[t0 + 3 + k]);
        }
        qa.h[3] = __float2half(0.0f); qa.h[7] = __float2half(0.0f);
        qb.h[3] = __float2half(0.0f); qb.h[7] = __float2half(0.0f);
        size_t rec = (size_t)(f * 512 + y) * 512 + x0 + tid;
        bg1n[rec * 2 + 0] = qa.f4;
        bg1n[rec * 2 + 1] = qb.f4;
        return;
    }

    // ---- horizontal blur branch: 2 rows per block ----
    float (*rows)[2][384] = (float (*)[2][384])sm;
    float (*wS)[32] = (float (*)[32])(sm + 1536);

    int bid  = b - 6144;               // 0..383
    int unit = tid >> 7;               // 0 or 1
    int lane = tid & 127;
    int face = bid / 64;
    int yrow = (bid % 64) * 2 + unit;

    weights_inline(tid, wS);

    int ynext = min(yrow + 1, 127);
    const float* srcA = bg0 + (size_t)(face * 128 + yrow) * 384;
    const float* srcB = bg0 + (size_t)(face * 128 + ynext) * 384;
    for (int k = lane; k < 384; k += 128) {
        rows[unit][0][k] = srcA[k];
        rows[unit][1][k] = srcB[k];
    }
    __syncthreads();

    int x = lane;
    float a[4][3] = {};
    for (int t = 0; t < KSIZE; ++t) {
        int xx = x + t - HRAD;
        if (xx >= 0 && xx < 128) {
            float r0 = rows[unit][0][xx * 3 + 0];
            float r1 = rows[unit][0][xx * 3 + 1];
            float r2 = rows[unit][0][xx * 3 + 2];
#pragma unroll
            for (int l = 0; l < 4; ++l) {
                float w = wS[l][t];
                a[l][0] += w * r0; a[l][1] += w * r1; a[l][2] += w * r2;
            }
        }
    }
    size_t idx = (size_t)(face * 128 + yrow) * 128 + x;
    H8U ta, tb;
#pragma unroll
    for (int l = 0; l < 2; ++l) {
        ta.h[l * 4 + 0] = __float2half(a[l][0]);
        ta.h[l * 4 + 1] = __float2half(a[l][1]);
        ta.h[l * 4 + 2] = __float2half(a[l][2]);
        ta.h[l * 4 + 3] = __float2half(0.0f);
        tb.h[l * 4 + 0] = __float2half(a[2 + l][0]);
        tb.h[l * 4 + 1] = __float2half(a[2 + l][1]);
        tb.h[l * 4 + 2] = __float2half(a[2 + l][2]);
        tb.h[l * 4 + 3] = __float2half(0.0f);
    }
    tmpH[idx * 2 + 0] = ta.f4;
    tmpH[idx * 2 + 1] = tb.f4;

    // bg0 neighborhood record for (x, yrow)
    int x1 = min(x + 1, 127);
    H8U qa, qb;
#pragma unroll
    for (int k = 0; k < 3; ++k) {
        qa.h[k]     = __float2half(rows[unit][0][x * 3 + k]);
        qa.h[4 + k] = __float2half(rows[unit][0][x1 * 3 + k]);
        qb.h[k]     = __float2half(rows[unit][1][x * 3 + k]);
        qb.h[4 + k] = __float2half(rows[unit][1][x1 * 3 + k]);
    }
    qa.h[3] = __float2half(0.0f); qa.h[7] = __float2half(0.0f);
    qb.h[3] = __float2half(0.0f); qb.h[7] = __float2half(0.0f);
    bg0n[idx * 2 + 0] = qa.f4;
    bg0n[idx * 2 + 1] = qb.f4;
}

// ---------------------------------------------------------------------------
// Vertical blur: one output row per block; 2 float4 loads per tap row.
// ---------------------------------------------------------------------------
__global__ __launch_bounds__(128)
void blur_v4(const float4* __restrict__ tmpH, float4* __restrict__ blurp) {
    __shared__ float wS[4][32];
    int bid  = blockIdx.x;
    int yrow = bid & 127;
    int face = bid >> 7;
    int tid  = threadIdx.x;

    weights_inline(tid, wS);
    __syncthreads();

    int x = tid;
    float acc[12] = {};
    int ylo = max(yrow - HRAD, 0);
    int yhi = min(yrow + HRAD, 127);
    for (int yy = ylo; yy <= yhi; ++yy) {
        int t = yy - yrow + HRAD;
        size_t idx = (size_t)(face * 128 + yy) * 128 + x;
        H8U qa, qb;
        qa.f4 = tmpH[idx * 2 + 0];
        qb.f4 = tmpH[idx * 2 + 1];
        float w0 = wS[0][t], w1 = wS[1][t], w2 = wS[2][t], w3 = wS[3][t];
        acc[0]  += w0 * __half2float(qa.h[0]);
        acc[1]  += w0 * __half2float(qa.h[1]);
        acc[2]  += w0 * __half2float(qa.h[2]);
        acc[3]  += w1 * __half2float(qa.h[4]);
        acc[4]  += w1 * __half2float(qa.h[5]);
        acc[5]  += w1 * __half2float(qa.h[6]);
        acc[6]  += w2 * __half2float(qb.h[0]);
        acc[7]  += w2 * __half2float(qb.h[1]);
        acc[8]  += w2 * __half2float(qb.h[2]);
        acc[9]  += w3 * __half2float(qb.h[4]);
        acc[10] += w3 * __half2float(qb.h[5]);
        acc[11] += w3 * __half2float(qb.h[6]);
    }

    H8U ra, rb;
#pragma unroll
    for (int l = 0; l < 2; ++l) {
        ra.h[l * 4 + 0] = __float2half(acc[l * 3 + 0]);
        ra.h[l * 4 + 1] = __float2half(acc[l * 3 + 1]);
        ra.h[l * 4 + 2] = __float2half(acc[l * 3 + 2]);
        ra.h[l * 4 + 3] = __float2half(0.0f);
        rb.h[l * 4 + 0] = __float2half(acc[6 + l * 3 + 0]);
        rb.h[l * 4 + 1] = __float2half(acc[6 + l * 3 + 1]);
        rb.h[l * 4 + 2] = __float2half(acc[6 + l * 3 + 2]);
        rb.h[l * 4 + 3] = __float2half(0.0f);
    }
    int rec = ((face * 64 + (yrow >> 1)) * 128 + x) * 2 + (yrow & 1);
    blurp[(size_t)rec * 2 + 0] = ra.f4;
    blurp[(size_t)rec * 2 + 1] = rb.f4;
}

// ---------------------------------------------------------------------------
// Per-ray shading body (r9-proven, byte-identical math)
// ---------------------------------------------------------------------------
__device__ inline void shade_one(float x, float y, float z, float sa,
                                 const float4* __restrict__ bg0n,
                                 const float4* __restrict__ bg1n,
                                 const float4* __restrict__ blurp,
                                 float* __restrict__ R) {
    int face; float u, v;
    cube_coords(x, y, z, face, u, v);

    const float saTexel = (float)(4.0 * M_PI / (6.0 * 512.0 * 512.0));
    float m = logf(sa / saTexel);
    m = m / 1.3862943611198906f;   // f32(log(4))
    m = m * 0.5f;
    m = fminf(fmaxf(m, 0.0f), 3.0f);

    if (m >= 2.0f) {
        BLR b = bl_rec(u, v, face);
        H8U q00a, q00b, q10a, q10b, q01a, q01b, q11a, q11b;
        q00a.f4 = blurp[b.r00 * 2 + 0]; q00b.f4 = blurp[b.r00 * 2 + 1];
        q10a.f4 = blurp[b.r10 * 2 + 0]; q10b.f4 = blurp[b.r10 * 2 + 1];
        q01a.f4 = blurp[b.r01 * 2 + 0]; q01b.f4 = blurp[b.r01 * 2 + 1];
        q11a.f4 = blurp[b.r11 * 2 + 0]; q11b.f4 = blurp[b.r11 * 2 + 1];

        float w0 = 1.0f - fminf(fabsf(3.0f - m), 1.0f);
        float w1 = 1.0f - fminf(fabsf(2.5f - m), 1.0f);
        float w2 = 1.0f - fminf(fabsf(2.0f - m), 1.0f);
        float w3 = 1.0f - fminf(fabsf(1.5f - m), 1.0f);

        float b0 = 0.f, b1 = 0.f, b2 = 0.f;
        accum_level(q00a, q10a, q01a, q11a, 0, w0, b.wx, b.wy, b0, b1, b2);
        accum_level(q00a, q10a, q01a, q11a, 4, w1, b.wx, b.wy, b0, b1, b2);
        accum_level(q00b, q10b, q01b, q11b, 0, w2, b.wx, b.wy, b0, b1, b2);
        accum_level(q00b, q10b, q01b, q11b, 4, w3, b.wx, b.wy, b0, b1, b2);

        float denom = fmaxf(w0 + w1 + w2 + w3, 1e-8f);
        R[0] = b0 / denom; R[1] = b1 / denom; R[2] = b2 / denom;
    } else {
        int r0i; float wx0, wy0;
        nb_setup(u, v, 128, face, r0i, wx0, wy0);
        int r1i; float wx1, wy1;
        nb_setup(u, v, 512, face, r1i, wx1, wy1);
        float c0[3], c1[3];
        nb_fetch(bg0n, r0i, wx0, wy0, c0);
        nb_fetch(bg1n, r1i, wx1, wy1, c1);
        R[0] = c0[0] + 0.5f * c1[0];
        R[1] = c0[1] + 0.5f * c1[1];
        R[2] = c0[2] + 0.5f * c1[2];
    }
}

// ---------------------------------------------------------------------------
// Shade: 4 rays per thread, vectorized stream I/O.
// ---------------------------------------------------------------------------
__global__ __launch_bounds__(256)
void shade4(const float4* __restrict__ vd4, const float4* __restrict__ sa4,
            const float4* __restrict__ bg0n, const float4* __restrict__ bg1n,
            const float4* __restrict__ blurp, float4* __restrict__ out4,
            int nquads) {
    int q = blockIdx.x * blockDim.x + threadIdx.x;
    if (q >= nquads) return;

    float4 a = vd4[3 * q + 0];
    float4 b = vd4[3 * q + 1];
    float4 c = vd4[3 * q + 2];
    float4 s = sa4[q];

    float X[4] = {a.x, a.w, b.z, c.y};
    float Y[4] = {a.y, b.x, b.w, c.z};
    float Z[4] = {a.z, b.y, c.x, c.w};
    float S[4] = {s.x, s.y, s.z, s.w};

    float R[12];
#pragma unroll
    for (int r = 0; r < 4; ++r) {
        shade_one(X[r], Y[r], Z[r], S[r], bg0n, bg1n, blurp, &R[3 * r]);
    }

    out4[3 * q + 0] = make_float4(R[0], R[1], R[2],  R[3]);
    out4[3 * q + 1] = make_float4(R[4], R[5], R[6],  R[7]);
    out4[3 * q + 2] = make_float4(R[8], R[9], R[10], R[11]);
}

// ---------------------------------------------------------------------------
extern "C" void kernel_launch(void* const* d_in, const int* in_sizes, int n_in,
                              void* d_out, int out_size, void* d_ws, size_t ws_size,
                              hipStream_t stream) {
    const float* viewdirs = (const float*)d_in[0];   // (B,3)
    const float* saSample = (const float*)d_in[1];   // (B,1)
    const float* bg0      = (const float*)d_in[2];   // (6,128,128,3)
    const float* bg1      = (const float*)d_in[3];   // (6,512,512,3)
    float* out = (float*)d_out;

    int B = in_sizes[0] / 3;          // 2097152
    int nquads = B / 4;

    // ws layout (59.3 MB; tier-A size proven available in r9):
    //   blurp : 196,608 float4  (3.0 MB)
    //   bg0n  : 196,608 float4  (3.0 MB)
    //   bg1n  : 3,145,728 float4 (50.3 MB)
    //   tmpH  : 196,608 float4  (3.0 MB)
    float4* blurp = (float4*)d_ws;
    float4* bg0n  = blurp + 196608;
    float4* bg1n  = bg0n + 196608;
    float4* tmpH  = bg1n + 3145728;

    prep1<<<6528, 256, 0, stream>>>(bg0, bg1, tmpH, bg0n, bg1n);
    blur_v4<<<6 * 128, 128, 0, stream>>>(tmpH, blurp);

    int blocks = (nquads + 255) / 256;
    shade4<<<blocks, 256, 0, stream>>>((const float4*)viewdirs,
                                       (const float4*)saSample,
                                       bg0n, bg1n, blurp,
                                       (float4*)out, nquads);
}

// Round 12
// 82.153 us; speedup vs baseline: 1.6712x; 1.2851x over previous
//
#include <hip/hip_runtime.h>
#include <hip/hip_fp16.h>
#include <math.h>

#define KSIZE 31
#define HRAD 15

#define QSCALE (1023.0f / 0.75f)
#define QINV   (0.75f / 1023.0f)
#define QOFF   0.25f

union H8U { float4 f4; __half h[8]; };

// ---------------------------------------------------------------------------
// 10-bit fixed-point RGB pack/unpack (range [-0.25, 0.5])
// ---------------------------------------------------------------------------
__device__ inline unsigned quant3(float r, float g, float b) {
    int qr = (int)((r + QOFF) * QSCALE + 0.5f);
    int qg = (int)((g + QOFF) * QSCALE + 0.5f);
    int qb = (int)((b + QOFF) * QSCALE + 0.5f);
    qr = min(max(qr, 0), 1023);
    qg = min(max(qg, 0), 1023);
    qb = min(max(qb, 0), 1023);
    return (unsigned)(qr | (qg << 10) | (qb << 20));
}

__device__ inline float deqc(unsigned q, int sh) {
    return (float)((q >> sh) & 1023u) * QINV - QOFF;
}

// ---------------------------------------------------------------------------
// Cube-map coordinate math (mirrors reference cube_sample exactly, f32)
// ---------------------------------------------------------------------------
__device__ inline void cube_coords(float x, float y, float z,
                                   int& face, float& u, float& v) {
    float ax = fabsf(x), ay = fabsf(y), az = fabsf(z);
    bool is_x = (ax >= ay) && (ax >= az);
    bool is_y = (!is_x) && (ay >= az);
    float ma, sc, tc;
    if (is_x) {
        if (x >= 0.0f) { face = 0; sc = -z; } else { face = 1; sc = z; }
        ma = ax; tc = -y;
    } else if (is_y) {
        if (y >= 0.0f) { face = 2; tc = z; } else { face = 3; tc = -z; }
        ma = ay; sc = x;
    } else {
        if (z >= 0.0f) { face = 4; sc = x; } else { face = 5; sc = -x; }
        ma = az; tc = -y;
    }
    float inv = 1.0f / fmaxf(ma, 1e-12f);
    u = 0.5 * (sc * inv + 1.0f);
    v = 0.5 * (tc * inv + 1.0f);
}

// corner-record bilinear setup: corners baked; left/top edge -> wx/wy = 0
__device__ inline void nbq_setup(float u, float v, int HW, int face,
                                 int& rec, float& wx, float& wy) {
    float fx = u * (float)HW - 0.5f;
    float fy = v * (float)HW - 0.5f;
    float x0 = floorf(fx), y0 = floorf(fy);
    wx = fx - x0;
    wy = fy - y0;
    int xi = (int)x0, yi = (int)y0;
    if (xi < 0) { xi = 0; wx = 0.0f; }
    if (yi < 0) { yi = 0; wy = 0.0f; }
    rec = (face * HW + yi) * HW + xi;
}

// ---------------------------------------------------------------------------
// Inline f32 Gaussian weights (tid 0..127 -> lvl=tid/32, tap=tid%32)
// ---------------------------------------------------------------------------
__device__ inline void weights_inline(int tid, float wS[4][32]) {
    const float ss[4] = {8.f, 4.f, 2.f, 1.f};
    int lvl = (tid >> 5) & 3;
    int tap = tid & 31;
    float d = (float)tap - 15.0f;
    float q = d / ss[lvl];
    float g = (tap < KSIZE) ? expf(-0.5f * q * q) : 0.0f;
    float s = g;
#pragma unroll
    for (int k = 16; k; k >>= 1) s += __shfl_xor(s, k, 32);
    if (tid < 128) wS[lvl][tap] = g / s;
}

// ---------------------------------------------------------------------------
// FUSED prep kernel:
//   blocks [0, 6144)    : bg1 corner-record pack (uint4 RGB10), row-run.
//   blocks [6144, 6528) : horizontal 4-level blur (2 rows/block) + bg0q emit
// tmpH: per 128-texel 32B f16 = {lvl0,lvl1 | lvl2,lvl3} RGB halves
// ---------------------------------------------------------------------------
__global__ __launch_bounds__(256)
void prep1(const float* __restrict__ bg0, const float* __restrict__ bg1,
           float4* __restrict__ tmpH, uint4* __restrict__ bg0q,
           uint4* __restrict__ bg1q) {
    __shared__ float sm[1664];
    int b = blockIdx.x;
    int tid = threadIdx.x;

    if (b < 6144) {
        // ---- bg1 pack: one 256-texel row segment per block ----
        float* smA = sm;          // row y   : 771 floats
        float* smB = sm + 771;    // row y+1 : 771 floats
        int half = b & 1;
        int y    = (b >> 1) & 511;
        int f    = b >> 10;
        int x0   = half * 256;
        int yn   = min(y + 1, 511);
        const float* rowA = bg1 + (size_t)(f * 512 + y)  * 1536;
        const float* rowB = bg1 + (size_t)(f * 512 + yn) * 1536;
        for (int k = tid; k < 771; k += 256) {
            int t = k / 3;
            int c = k - t * 3;
            int gx = min(x0 + t, 511);
            smA[k] = rowA[gx * 3 + c];
            smB[k] = rowB[gx * 3 + c];
        }
        __syncthreads();
        int t0 = tid * 3;
        uint4 r;
        r.x = quant3(smA[t0 + 0], smA[t0 + 1], smA[t0 + 2]);
        r.y = quant3(smA[t0 + 3], smA[t0 + 4], smA[t0 + 5]);
        r.z = quant3(smB[t0 + 0], smB[t0 + 1], smB[t0 + 2]);
        r.w = quant3(smB[t0 + 3], smB[t0 + 4], smB[t0 + 5]);
        bg1q[(size_t)(f * 512 + y) * 512 + x0 + tid] = r;
        return;
    }

    // ---- horizontal blur branch: 2 rows per block ----
    float (*rows)[2][384] = (float (*)[2][384])sm;
    float (*wS)[32] = (float (*)[32])(sm + 1536);

    int bid  = b - 6144;               // 0..383
    int unit = tid >> 7;               // 0 or 1
    int lane = tid & 127;
    int face = bid / 64;
    int yrow = (bid % 64) * 2 + unit;

    weights_inline(tid, wS);

    int ynext = min(yrow + 1, 127);
    const float* srcA = bg0 + (size_t)(face * 128 + yrow) * 384;
    const float* srcB = bg0 + (size_t)(face * 128 + ynext) * 384;
    for (int k = lane; k < 384; k += 128) {
        rows[unit][0][k] = srcA[k];
        rows[unit][1][k] = srcB[k];
    }
    __syncthreads();

    int x = lane;
    float a[4][3] = {};
    for (int t = 0; t < KSIZE; ++t) {
        int xx = x + t - HRAD;
        if (xx >= 0 && xx < 128) {
            float r0 = rows[unit][0][xx * 3 + 0];
            float r1 = rows[unit][0][xx * 3 + 1];
            float r2 = rows[unit][0][xx * 3 + 2];
#pragma unroll
            for (int l = 0; l < 4; ++l) {
                float w = wS[l][t];
                a[l][0] += w * r0; a[l][1] += w * r1; a[l][2] += w * r2;
            }
        }
    }
    size_t idx = (size_t)(face * 128 + yrow) * 128 + x;
    H8U ta, tb;
#pragma unroll
    for (int l = 0; l < 2; ++l) {
        ta.h[l * 4 + 0] = __float2half(a[l][0]);
        ta.h[l * 4 + 1] = __float2half(a[l][1]);
        ta.h[l * 4 + 2] = __float2half(a[l][2]);
        ta.h[l * 4 + 3] = __float2half(0.0f);
        tb.h[l * 4 + 0] = __float2half(a[2 + l][0]);
        tb.h[l * 4 + 1] = __float2half(a[2 + l][1]);
        tb.h[l * 4 + 2] = __float2half(a[2 + l][2]);
        tb.h[l * 4 + 3] = __float2half(0.0f);
    }
    tmpH[idx * 2 + 0] = ta.f4;
    tmpH[idx * 2 + 1] = tb.f4;

    // bg0 corner record for (x, yrow)
    int x1 = min(x + 1, 127);
    uint4 r;
    r.x = quant3(rows[unit][0][x * 3 + 0], rows[unit][0][x * 3 + 1], rows[unit][0][x * 3 + 2]);
    r.y = quant3(rows[unit][0][x1 * 3 + 0], rows[unit][0][x1 * 3 + 1], rows[unit][0][x1 * 3 + 2]);
    r.z = quant3(rows[unit][1][x * 3 + 0], rows[unit][1][x * 3 + 1], rows[unit][1][x * 3 + 2]);
    r.w = quant3(rows[unit][1][x1 * 3 + 0], rows[unit][1][x1 * 3 + 1], rows[unit][1][x1 * 3 + 2]);
    bg0q[idx] = r;
}

// ---------------------------------------------------------------------------
// Vertical blur: one output row per block; emits ONE uint4 level-record
// (4 levels x RGB10) per texel.  blurq rec = (face*128+y)*128+x.
// ---------------------------------------------------------------------------
__global__ __launch_bounds__(128)
void blur_v4(const float4* __restrict__ tmpH, uint4* __restrict__ blurq) {
    __shared__ float wS[4][32];
    int bid  = blockIdx.x;
    int yrow = bid & 127;
    int face = bid >> 7;
    int tid  = threadIdx.x;

    weights_inline(tid, wS);
    __syncthreads();

    int x = tid;
    float acc[12] = {};
    int ylo = max(yrow - HRAD, 0);
    int yhi = min(yrow + HRAD, 127);
    for (int yy = ylo; yy <= yhi; ++yy) {
        int t = yy - yrow + HRAD;
        size_t idx = (size_t)(face * 128 + yy) * 128 + x;
        H8U qa, qb;
        qa.f4 = tmpH[idx * 2 + 0];
        qb.f4 = tmpH[idx * 2 + 1];
        float w0 = wS[0][t], w1 = wS[1][t], w2 = wS[2][t], w3 = wS[3][t];
        acc[0]  += w0 * __half2float(qa.h[0]);
        acc[1]  += w0 * __half2float(qa.h[1]);
        acc[2]  += w0 * __half2float(qa.h[2]);
        acc[3]  += w1 * __half2float(qa.h[4]);
        acc[4]  += w1 * __half2float(qa.h[5]);
        acc[5]  += w1 * __half2float(qa.h[6]);
        acc[6]  += w2 * __half2float(qb.h[0]);
        acc[7]  += w2 * __half2float(qb.h[1]);
        acc[8]  += w2 * __half2float(qb.h[2]);
        acc[9]  += w3 * __half2float(qb.h[4]);
        acc[10] += w3 * __half2float(qb.h[5]);
        acc[11] += w3 * __half2float(qb.h[6]);
    }

    uint4 r;
    r.x = quant3(acc[0], acc[1], acc[2]);
    r.y = quant3(acc[3], acc[4], acc[5]);
    r.z = quant3(acc[6], acc[7], acc[8]);
    r.w = quant3(acc[9], acc[10], acc[11]);
    blurq[(size_t)(face * 128 + yrow) * 128 + x] = r;
}

// ---------------------------------------------------------------------------
// Per-ray shading: masked = 4 uint4 loads (L2-resident blurq);
// unmasked = 2 uint4 loads (bg0q resident + bg1q 1 miss).
// ---------------------------------------------------------------------------
__device__ inline void shade_one(float x, float y, float z, float sa,
                                 const uint4* __restrict__ bg0q,
                                 const uint4* __restrict__ bg1q,
                                 const uint4* __restrict__ blurq,
                                 float* __restrict__ R) {
    int face; float u, v;
    cube_coords(x, y, z, face, u, v);

    const float saTexel = (float)(4.0 * M_PI / (6.0 * 512.0 * 512.0));
    float m = logf(sa / saTexel);
    m = m / 1.3862943611198906f;   // f32(log(4))
    m = m * 0.5f;
    m = fminf(fmaxf(m, 0.0f), 3.0f);

    if (m >= 2.0f) {
        float fx = u * 128.0f - 0.5f;
        float fy = v * 128.0f - 0.5f;
        float xf = floorf(fx), yf = floorf(fy);
        float wx = fx - xf, wy = fy - yf;
        int x0i = min(max((int)xf, 0), 127);
        int x1i = min(max((int)xf + 1, 0), 127);
        int y0i = min(max((int)yf, 0), 127);
        int y1i = min(max((int)yf + 1, 0), 127);
        int base = face << 14;
        uint4 q00 = blurq[base + y0i * 128 + x0i];
        uint4 q10 = blurq[base + y0i * 128 + x1i];
        uint4 q01 = blurq[base + y1i * 128 + x0i];
        uint4 q11 = blurq[base + y1i * 128 + x1i];

        float w0 = 1.0f - fminf(fabsf(3.0f - m), 1.0f);
        float w1 = 1.0f - fminf(fabsf(2.5f - m), 1.0f);
        float w2 = 1.0f - fminf(fabsf(2.0f - m), 1.0f);
        float w3 = 1.0f - fminf(fabsf(1.5f - m), 1.0f);
        float inv = 1.0f / fmaxf(w0 + w1 + w2 + w3, 1e-8f);

#pragma unroll
        for (int c = 0; c < 3; ++c) {
            int sh = c * 10;
            float v00 = w0 * deqc(q00.x, sh) + w1 * deqc(q00.y, sh) +
                        w2 * deqc(q00.z, sh) + w3 * deqc(q00.w, sh);
            float v10 = w0 * deqc(q10.x, sh) + w1 * deqc(q10.y, sh) +
                        w2 * deqc(q10.z, sh) + w3 * deqc(q10.w, sh);
            float v01 = w0 * deqc(q01.x, sh) + w1 * deqc(q01.y, sh) +
                        w2 * deqc(q01.z, sh) + w3 * deqc(q01.w, sh);
            float v11 = w0 * deqc(q11.x, sh) + w1 * deqc(q11.y, sh) +
                        w2 * deqc(q11.z, sh) + w3 * deqc(q11.w, sh);
            float top = v00 * (1.0f - wx) + v10 * wx;
            float bot = v01 * (1.0f - wx) + v11 * wx;
            R[c] = (top * (1.0f - wy) + bot * wy) * inv;
        }
    } else {
        int r0; float wx0, wy0;
        nbq_setup(u, v, 128, face, r0, wx0, wy0);
        int r1; float wx1, wy1;
        nbq_setup(u, v, 512, face, r1, wx1, wy1);
        uint4 p0 = bg0q[r0];
        uint4 p1 = bg1q[r1];
#pragma unroll
        for (int c = 0; c < 3; ++c) {
            int sh = c * 10;
            float t0 = deqc(p0.x, sh) * (1.0f - wx0) + deqc(p0.y, sh) * wx0;
            float b0 = deqc(p0.z, sh) * (1.0f - wx0) + deqc(p0.w, sh) * wx0;
            float c0 = t0 * (1.0f - wy0) + b0 * wy0;
            float t1 = deqc(p1.x, sh) * (1.0f - wx1) + deqc(p1.y, sh) * wx1;
            float b1 = deqc(p1.z, sh) * (1.0f - wx1) + deqc(p1.w, sh) * wx1;
            float c1 = t1 * (1.0f - wy1) + b1 * wy1;
            R[c] = c0 + 0.5f * c1;
        }
    }
}

// ---------------------------------------------------------------------------
// Shade: 4 rays per thread, vectorized stream I/O.
// ---------------------------------------------------------------------------
__global__ __launch_bounds__(256)
void shade4(const float4* __restrict__ vd4, const float4* __restrict__ sa4,
            const uint4* __restrict__ bg0q, const uint4* __restrict__ bg1q,
            const uint4* __restrict__ blurq, float4* __restrict__ out4,
            int nquads) {
    int q = blockIdx.x * blockDim.x + threadIdx.x;
    if (q >= nquads) return;

    float4 a = vd4[3 * q + 0];
    float4 b = vd4[3 * q + 1];
    float4 c = vd4[3 * q + 2];
    float4 s = sa4[q];

    float X[4] = {a.x, a.w, b.z, c.y};
    float Y[4] = {a.y, b.x, b.w, c.z};
    float Z[4] = {a.z, b.y, c.x, c.w};
    float S[4] = {s.x, s.y, s.z, s.w};

    float R[12];
#pragma unroll
    for (int r = 0; r < 4; ++r) {
        shade_one(X[r], Y[r], Z[r], S[r], bg0q, bg1q, blurq, &R[3 * r]);
    }

    out4[3 * q + 0] = make_float4(R[0], R[1], R[2],  R[3]);
    out4[3 * q + 1] = make_float4(R[4], R[5], R[6],  R[7]);
    out4[3 * q + 2] = make_float4(R[8], R[9], R[10], R[11]);
}

// ---------------------------------------------------------------------------
extern "C" void kernel_launch(void* const* d_in, const int* in_sizes, int n_in,
                              void* d_out, int out_size, void* d_ws, size_t ws_size,
                              hipStream_t stream) {
    const float* viewdirs = (const float*)d_in[0];   // (B,3)
    const float* saSample = (const float*)d_in[1];   // (B,1)
    const float* bg0      = (const float*)d_in[2];   // (6,128,128,3)
    const float* bg1      = (const float*)d_in[3];   // (6,512,512,3)
    float* out = (float*)d_out;

    int B = in_sizes[0] / 3;          // 2097152
    int nquads = B / 4;

    // ws layout (31.2 MB):
    //   blurq : 98,304 uint4    (1.5 MB)
    //   bg0q  : 98,304 uint4    (1.5 MB)
    //   bg1q  : 1,572,864 uint4 (25.2 MB)
    //   tmpH  : 196,608 float4  (3.0 MB)
    uint4*  blurq = (uint4*)d_ws;
    uint4*  bg0q  = blurq + 98304;
    uint4*  bg1q  = bg0q + 98304;
    float4* tmpH  = (float4*)(bg1q + 1572864);

    prep1<<<6528, 256, 0, stream>>>(bg0, bg1, tmpH, bg0q, bg1q);
    blur_v4<<<6 * 128, 128, 0, stream>>>(tmpH, blurq);

    int blocks = (nquads + 255) / 256;
    shade4<<<blocks, 256, 0, stream>>>((const float4*)viewdirs,
                                       (const float4*)saSample,
                                       bg0q, bg1q, blurq,
                                       (float4*)out, nquads);
}